// Round 1
// baseline (278.276 us; speedup 1.0000x reference)
//
#include <hip/hip_runtime.h>
#include <hip/hip_bf16.h>

#define B_ 2
#define S_ 2048
#define D_ 1024
#define H_ 16
#define DK_ 64
#define M_ (B_*S_)   // 4096 rows
#define K_ D_        // 1024 reduction dim

typedef __attribute__((ext_vector_type(8))) short bf16x8;
typedef __attribute__((ext_vector_type(4))) float f32x4;

__device__ __forceinline__ unsigned short f2bf(float f) {
  unsigned u = __float_as_uint(f);
  u += 0x7fff + ((u >> 16) & 1);   // round-to-nearest-even
  return (unsigned short)(u >> 16);
}

// async global->LDS, 16B per lane. LDS dest must be wave-uniform base; HW writes
// base + lane*16 (linear). Generic->AS3 via integer truncation (low 32 bits of a
// flat LDS pointer are the LDS offset; shared aperture is 4GB-aligned).
__device__ __forceinline__ void gload_lds16(const void* g, void* l) {
  __builtin_amdgcn_global_load_lds(
      (const __attribute__((address_space(1))) unsigned int*)(unsigned long long)g,
      (__attribute__((address_space(3))) unsigned int*)(unsigned int)(unsigned long long)l,
      16, 0, 0);
}

// ---------------- fp32 -> bf16 convert ----------------
__global__ __launch_bounds__(256) void k_f2b(const float* __restrict__ src,
                                             unsigned short* __restrict__ dst, int n) {
  int i = (blockIdx.x * 256 + threadIdx.x) * 4;
  if (i >= n) return;
  float4 v = *(const float4*)(src + i);
  ushort4 o;
  o.x = f2bf(v.x); o.y = f2bf(v.y); o.z = f2bf(v.z); o.w = f2bf(v.w);
  *(ushort4*)(dst + i) = o;
}

// ---------------- RoPE cos/sin table: [S][32] ----------------
__global__ __launch_bounds__(256) void k_rope_tab(const int* __restrict__ pos,
                                                  float2* __restrict__ tab) {
  int t = blockIdx.x * 256 + threadIdx.x;   // S*32 threads
  int s = t >> 5, j = t & 31;
  float inv = powf(10000.0f, -(float)j / 32.0f);
  float ang = (float)pos[s] * inv;
  tab[t] = make_float2(cosf(ang), sinf(ang));
}

// ---------------- NT GEMM (m97 structure), fused epilogues ----------------
// MODE 0: out = x @ W_z^T for z = blockIdx.z in {0,1,2} (Wq,Wk,Wv); apply RoPE
//         for z<2; scatter bf16 to [B,H,S,DK].
// MODE 1: out = attn @ Wo^T -> fp32 row-major [M,D] (d_out).
template<int MODE>
__global__ __launch_bounds__(256) void k_gemm(
    const unsigned short* __restrict__ A,      // [M,K] bf16
    const unsigned short* __restrict__ Wall,   // 4 weight mats, each [D,K] bf16
    unsigned short* __restrict__ qkv,          // MODE 0 dst base
    float* __restrict__ fout,                  // MODE 1 dst
    const float2* __restrict__ tab)
{
  __shared__ unsigned short As[128*32];
  __shared__ unsigned short Bs[128*32];
  const int tid = threadIdx.x, lane = tid & 63, w = tid >> 6;
  const int wr = w >> 1, wc = w & 1;
  const int m0 = blockIdx.x * 128, n0 = blockIdx.y * 128;
  const int z = (MODE == 0) ? blockIdx.z : 3;
  const unsigned short* Ag = A + (size_t)m0 * K_;
  const unsigned short* Bg = Wall + (size_t)z * D_ * K_ + (size_t)n0 * K_;

  f32x4 acc[4][4];
#pragma unroll
  for (int m = 0; m < 4; ++m)
#pragma unroll
    for (int n = 0; n < 4; ++n) acc[m][n] = (f32x4){0.f, 0.f, 0.f, 0.f};

  const int sr = w*32 + (lane >> 2);   // staging row (+c*16)
  const int sc = (lane & 3) * 8;       // staging col (elements)

  for (int kt = 0; kt < K_; kt += 32) {
    __syncthreads();
#pragma unroll
    for (int c = 0; c < 2; ++c) {
      gload_lds16(Ag + (size_t)(sr + c*16)*K_ + kt + sc, &As[(w*32 + c*16)*32]);
      gload_lds16(Bg + (size_t)(sr + c*16)*K_ + kt + sc, &Bs[(w*32 + c*16)*32]);
    }
    __syncthreads();
    bf16x8 af[4], bfr[4];
#pragma unroll
    for (int m = 0; m < 4; ++m)
      af[m] = *(const bf16x8*)&As[(wr*64 + m*16 + (lane & 15))*32 + (lane >> 4)*8];
#pragma unroll
    for (int n = 0; n < 4; ++n)
      bfr[n] = *(const bf16x8*)&Bs[(wc*64 + n*16 + (lane & 15))*32 + (lane >> 4)*8];
#pragma unroll
    for (int m = 0; m < 4; ++m)
#pragma unroll
      for (int n = 0; n < 4; ++n)
        acc[m][n] = __builtin_amdgcn_mfma_f32_16x16x32_bf16(af[m], bfr[n], acc[m][n], 0, 0, 0);
  }

  if (MODE == 1) {
#pragma unroll
    for (int m = 0; m < 4; ++m)
#pragma unroll
      for (int n = 0; n < 4; ++n) {
        const int row0 = m0 + wr*64 + m*16 + (lane >> 4)*4;
        const int col  = n0 + wc*64 + n*16 + (lane & 15);
#pragma unroll
        for (int r = 0; r < 4; ++r)
          fout[(size_t)(row0 + r)*D_ + col] = acc[m][n][r];
      }
  } else {
    unsigned short* dst = qkv + (size_t)z * M_ * D_;
#pragma unroll
    for (int m = 0; m < 4; ++m)
#pragma unroll
      for (int n = 0; n < 4; ++n) {
        const int row0 = m0 + wr*64 + m*16 + (lane >> 4)*4;
        const int col  = n0 + wc*64 + n*16 + (lane & 15);
        const int h = col >> 6, d = col & 63;
        const float sgn = (d & 1) ? 1.0f : -1.0f;
#pragma unroll
        for (int r = 0; r < 4; ++r) {
          const int row = row0 + r;
          const int b = row >> 11, s = row & (S_ - 1);
          float v  = acc[m][n][r];
          float pv = __shfl_xor(v, 1);          // pair partner: col^1 == lane^1
          float ov;
          if (z < 2) {
            float2 cs = tab[s*32 + (d >> 1)];
            ov = v * cs.x + sgn * pv * cs.y;    // even: v*c - p*s ; odd: v*c + p*s
          } else {
            ov = v;
          }
          dst[((size_t)(b*H_ + h)*S_ + s)*DK_ + d] = f2bf(ov);
        }
      }
  }
}

// ---------------- causal flash attention ----------------
// grid (S/64, B*H), 256 threads (4 waves x 16 q-rows each), KV blocks of 64.
__global__ __launch_bounds__(256) void k_attn(
    const unsigned short* __restrict__ Qg,   // [B*H, S, DK]
    const unsigned short* __restrict__ Kg,
    const unsigned short* __restrict__ Vg,
    unsigned short* __restrict__ Og)         // [B, S, D]
{
  __shared__ unsigned short Qs[64*72];
  __shared__ unsigned short Ks[64*72];
  __shared__ unsigned short Vt[64*72];   // V transposed: Vt[d][kv]
  __shared__ unsigned short Ps[64*72];

  const int tid = threadIdx.x, lane = tid & 63, w = tid >> 6;
  const int q0 = blockIdx.x * 64;
  const int bh = blockIdx.y;
  const unsigned short* Qp = Qg + ((size_t)bh*S_ + q0)*DK_;
  const unsigned short* Kp = Kg + (size_t)bh*S_*DK_;
  const unsigned short* Vp = Vg + (size_t)bh*S_*DK_;

  {
    const int r = tid >> 3, c = (tid & 7)*8;
#pragma unroll
    for (int it = 0; it < 2; ++it)
      *(uint4*)&Qs[(r + it*32)*72 + c] = *(const uint4*)(Qp + (size_t)(r + it*32)*DK_ + c);
  }

  f32x4 oacc[4];
  float mrow[4], lrow[4];
#pragma unroll
  for (int n = 0; n < 4; ++n) oacc[n] = (f32x4){0.f, 0.f, 0.f, 0.f};
#pragma unroll
  for (int r = 0; r < 4; ++r) { mrow[r] = -INFINITY; lrow[r] = 0.f; }

  const int nkv = (q0 >> 6) + 1;
  for (int t = 0; t < nkv; ++t) {
    const int kv0 = t*64;
    __syncthreads();   // protect Ks/Vt from previous iteration's readers
    {
      const int r = tid >> 3, c = (tid & 7)*8;
#pragma unroll
      for (int it = 0; it < 2; ++it) {
        const int rr = r + it*32;
        *(uint4*)&Ks[rr*72 + c] = *(const uint4*)(Kp + (size_t)(kv0 + rr)*DK_ + c);
        uint4 vv = *(const uint4*)(Vp + (size_t)(kv0 + rr)*DK_ + c);
        const unsigned short* pe = (const unsigned short*)&vv;
#pragma unroll
        for (int j = 0; j < 8; ++j) Vt[(c + j)*72 + rr] = pe[j];
      }
    }
    __syncthreads();

    // ---- QK^T (NT): scores[q][k], q-strip = w*16..+15
    bf16x8 aq[2];
#pragma unroll
    for (int kk = 0; kk < 2; ++kk)
      aq[kk] = *(const bf16x8*)&Qs[(w*16 + (lane & 15))*72 + kk*32 + (lane >> 4)*8];

    f32x4 sc4[4];
#pragma unroll
    for (int n = 0; n < 4; ++n) {
      sc4[n] = (f32x4){0.f, 0.f, 0.f, 0.f};
#pragma unroll
      for (int kk = 0; kk < 2; ++kk) {
        bf16x8 bk = *(const bf16x8*)&Ks[(n*16 + (lane & 15))*72 + kk*32 + (lane >> 4)*8];
        sc4[n] = __builtin_amdgcn_mfma_f32_16x16x32_bf16(aq[kk], bk, sc4[n], 0, 0, 0);
      }
    }

    // ---- scale + causal mask + online softmax
    const int qr0 = q0 + w*16 + (lane >> 4)*4;
    const int kc0 = kv0 + (lane & 15);
    float pm[4] = {-INFINITY, -INFINITY, -INFINITY, -INFINITY};
#pragma unroll
    for (int n = 0; n < 4; ++n)
#pragma unroll
      for (int r = 0; r < 4; ++r) {
        float sv = sc4[n][r] * 0.125f;
        sv = (kc0 + n*16 <= qr0 + r) ? sv : -INFINITY;
        sc4[n][r] = sv;
        pm[r] = fmaxf(pm[r], sv);
      }
#pragma unroll
    for (int off = 1; off < 16; off <<= 1)
#pragma unroll
      for (int r = 0; r < 4; ++r)
        pm[r] = fmaxf(pm[r], __shfl_xor(pm[r], off));

    float alpha[4];
#pragma unroll
    for (int r = 0; r < 4; ++r) {
      float mn = fmaxf(mrow[r], pm[r]);
      alpha[r] = __expf(mrow[r] - mn);   // exp(-inf)=0 on first block
      mrow[r] = mn;
    }

    float psum[4] = {0.f, 0.f, 0.f, 0.f};
#pragma unroll
    for (int n = 0; n < 4; ++n)
#pragma unroll
      for (int r = 0; r < 4; ++r) {
        float p = __expf(sc4[n][r] - mrow[r]);
        sc4[n][r] = p;
        psum[r] += p;
      }
#pragma unroll
    for (int off = 1; off < 16; off <<= 1)
#pragma unroll
      for (int r = 0; r < 4; ++r)
        psum[r] += __shfl_xor(psum[r], off);

#pragma unroll
    for (int r = 0; r < 4; ++r) lrow[r] = lrow[r]*alpha[r] + psum[r];

    // P -> LDS (bf16), wave-local rows only (no barrier needed before re-read)
#pragma unroll
    for (int n = 0; n < 4; ++n)
#pragma unroll
      for (int r = 0; r < 4; ++r)
        Ps[(w*16 + (lane >> 4)*4 + r)*72 + n*16 + (lane & 15)] = f2bf(sc4[n][r]);

#pragma unroll
    for (int n = 0; n < 4; ++n)
#pragma unroll
      for (int r = 0; r < 4; ++r)
        oacc[n][r] *= alpha[r];

    // ---- PV: attn[q][d] += P[q][kv] * V[kv][d]
    bf16x8 ap[2];
#pragma unroll
    for (int kk = 0; kk < 2; ++kk)
      ap[kk] = *(const bf16x8*)&Ps[(w*16 + (lane & 15))*72 + kk*32 + (lane >> 4)*8];
#pragma unroll
    for (int n = 0; n < 4; ++n)
#pragma unroll
      for (int kk = 0; kk < 2; ++kk) {
        bf16x8 bv = *(const bf16x8*)&Vt[(n*16 + (lane & 15))*72 + kk*32 + (lane >> 4)*8];
        oacc[n] = __builtin_amdgcn_mfma_f32_16x16x32_bf16(ap[kk], bv, oacc[n], 0, 0, 0);
      }
  }

  const int b = bh >> 4, h = bh & 15;
#pragma unroll
  for (int n = 0; n < 4; ++n)
#pragma unroll
    for (int r = 0; r < 4; ++r) {
      const int s = q0 + w*16 + (lane >> 4)*4 + r;
      const int d = n*16 + (lane & 15);
      Og[((size_t)b*S_ + s)*D_ + h*DK_ + d] = f2bf(oacc[n][r] / lrow[r]);
    }
}

// ---------------- launcher ----------------
extern "C" void kernel_launch(void* const* d_in, const int* in_sizes, int n_in,
                              void* d_out, int out_size, void* d_ws, size_t ws_size,
                              hipStream_t stream) {
  const float* x = (const float*)d_in[0];
  const float* Wm[4] = {(const float*)d_in[1], (const float*)d_in[2],
                        (const float*)d_in[3], (const float*)d_in[4]};
  const int* tp = (const int*)d_in[5];
  float* out = (float*)d_out;

  unsigned short* ws = (unsigned short*)d_ws;
  const size_t MD = (size_t)M_ * D_;                 // 4M elements
  unsigned short* xb  = ws;                          // x bf16; reused as attn buffer
  unsigned short* wb  = ws + MD;                     // 4 weight mats bf16
  unsigned short* qws = ws + MD + 4*(size_t)D_*K_;   // Q,K,V each MD elements
  float2* tab = (float2*)(ws + MD + 4*(size_t)D_*K_ + 3*MD);  // [S][32]

  k_f2b<<<dim3((int)(MD/4/256)), 256, 0, stream>>>(x, xb, (int)MD);
  for (int i = 0; i < 4; ++i)
    k_f2b<<<dim3((int)((size_t)D_*K_/4/256)), 256, 0, stream>>>(Wm[i], wb + (size_t)i*D_*K_, D_*K_);
  k_rope_tab<<<dim3(S_*32/256), 256, 0, stream>>>(tp, tab);

  k_gemm<0><<<dim3(M_/128, D_/128, 3), 256, 0, stream>>>(xb, wb, qws, nullptr, tab);

  unsigned short* attn = xb;   // x no longer needed
  k_attn<<<dim3(S_/64, B_*H_), 256, 0, stream>>>(qws, qws + MD, qws + 2*MD, attn);

  k_gemm<1><<<dim3(M_/128, D_/128, 1), 256, 0, stream>>>(attn, wb, nullptr, out, tab);
}

// Round 2
// 215.165 us; speedup vs baseline: 1.2933x; 1.2933x over previous
//
#include <hip/hip_runtime.h>
#include <hip/hip_bf16.h>

#define B_ 2
#define S_ 2048
#define D_ 1024
#define H_ 16
#define DK_ 64
#define M_ (B_*S_)   // 4096 rows
#define K_ D_        // 1024 reduction dim

typedef __attribute__((ext_vector_type(8))) short bf16x8;
typedef __attribute__((ext_vector_type(4))) float f32x4;

__device__ __forceinline__ unsigned short f2bf(float f) {
  unsigned u = __float_as_uint(f);
  u += 0x7fff + ((u >> 16) & 1);   // round-to-nearest-even
  return (unsigned short)(u >> 16);
}

// async global->LDS, 16B per lane (GEMM staging only).
__device__ __forceinline__ void gload_lds16(const void* g, void* l) {
  __builtin_amdgcn_global_load_lds(
      (const __attribute__((address_space(1))) unsigned int*)(unsigned long long)g,
      (__attribute__((address_space(3))) unsigned int*)(unsigned int)(unsigned long long)l,
      16, 0, 0);
}

// ---------------- fp32 -> bf16 convert ----------------
__global__ __launch_bounds__(256) void k_f2b(const float* __restrict__ src,
                                             unsigned short* __restrict__ dst, int n) {
  int i = (blockIdx.x * 256 + threadIdx.x) * 4;
  if (i >= n) return;
  float4 v = *(const float4*)(src + i);
  ushort4 o;
  o.x = f2bf(v.x); o.y = f2bf(v.y); o.z = f2bf(v.z); o.w = f2bf(v.w);
  *(ushort4*)(dst + i) = o;
}

// ---------------- RoPE cos/sin table: [S][32] ----------------
__global__ __launch_bounds__(256) void k_rope_tab(const int* __restrict__ pos,
                                                  float2* __restrict__ tab) {
  int t = blockIdx.x * 256 + threadIdx.x;   // S*32 threads
  int s = t >> 5, j = t & 31;
  float inv = powf(10000.0f, -(float)j / 32.0f);
  float ang = (float)pos[s] * inv;
  tab[t] = make_float2(cosf(ang), sinf(ang));
}

// ---------------- NT GEMM (m97 structure), fused epilogues ----------------
// MODE 0: out = x @ W_z^T, z = blockIdx.z in {0,1,2}:
//   z<2  : RoPE, scatter bf16 to [B*H][S][DK]
//   z==2 : scatter bf16 TRANSPOSED to [B*H][DK][S]  (V^T for attention B-operand)
// MODE 1: out = attn @ Wo^T -> fp32 row-major [M,D] (d_out).
template<int MODE>
__global__ __launch_bounds__(256) void k_gemm(
    const unsigned short* __restrict__ A,      // [M,K] bf16
    const unsigned short* __restrict__ Wall,   // 4 weight mats, each [D,K] bf16
    unsigned short* __restrict__ qkv,          // MODE 0 dst base
    float* __restrict__ fout,                  // MODE 1 dst
    const float2* __restrict__ tab)
{
  __shared__ unsigned short As[128*32];
  __shared__ unsigned short Bs[128*32];
  const int tid = threadIdx.x, lane = tid & 63, w = tid >> 6;
  const int wr = w >> 1, wc = w & 1;
  const int m0 = blockIdx.x * 128, n0 = blockIdx.y * 128;
  const int z = (MODE == 0) ? blockIdx.z : 3;
  const unsigned short* Ag = A + (size_t)m0 * K_;
  const unsigned short* Bg = Wall + (size_t)z * D_ * K_ + (size_t)n0 * K_;

  f32x4 acc[4][4];
#pragma unroll
  for (int m = 0; m < 4; ++m)
#pragma unroll
    for (int n = 0; n < 4; ++n) acc[m][n] = (f32x4){0.f, 0.f, 0.f, 0.f};

  const int sr = w*32 + (lane >> 2);   // staging row (+c*16)
  const int sc = (lane & 3) * 8;       // staging col (elements)

  for (int kt = 0; kt < K_; kt += 32) {
    __syncthreads();
#pragma unroll
    for (int c = 0; c < 2; ++c) {
      gload_lds16(Ag + (size_t)(sr + c*16)*K_ + kt + sc, &As[(w*32 + c*16)*32]);
      gload_lds16(Bg + (size_t)(sr + c*16)*K_ + kt + sc, &Bs[(w*32 + c*16)*32]);
    }
    __syncthreads();
    bf16x8 af[4], bfr[4];
#pragma unroll
    for (int m = 0; m < 4; ++m)
      af[m] = *(const bf16x8*)&As[(wr*64 + m*16 + (lane & 15))*32 + (lane >> 4)*8];
#pragma unroll
    for (int n = 0; n < 4; ++n)
      bfr[n] = *(const bf16x8*)&Bs[(wc*64 + n*16 + (lane & 15))*32 + (lane >> 4)*8];
#pragma unroll
    for (int m = 0; m < 4; ++m)
#pragma unroll
      for (int n = 0; n < 4; ++n)
        acc[m][n] = __builtin_amdgcn_mfma_f32_16x16x32_bf16(af[m], bfr[n], acc[m][n], 0, 0, 0);
  }

  if (MODE == 1) {
#pragma unroll
    for (int m = 0; m < 4; ++m)
#pragma unroll
      for (int n = 0; n < 4; ++n) {
        const int row0 = m0 + wr*64 + m*16 + (lane >> 4)*4;
        const int col  = n0 + wc*64 + n*16 + (lane & 15);
#pragma unroll
        for (int r = 0; r < 4; ++r)
          fout[(size_t)(row0 + r)*D_ + col] = acc[m][n][r];
      }
  } else {
    unsigned short* dst = qkv + (size_t)z * M_ * D_;
    if (z == 2) {
      // V^T: [B*H][DK][S], pack 4 consecutive s per lane (8B store)
#pragma unroll
      for (int m = 0; m < 4; ++m)
#pragma unroll
        for (int n = 0; n < 4; ++n) {
          const int row0 = m0 + wr*64 + m*16 + (lane >> 4)*4;
          const int col  = n0 + wc*64 + n*16 + (lane & 15);
          const int h = col >> 6, d = col & 63;
          const int b = row0 >> 11, s0 = row0 & (S_ - 1);
          ushort4 o;
          o.x = f2bf(acc[m][n][0]); o.y = f2bf(acc[m][n][1]);
          o.z = f2bf(acc[m][n][2]); o.w = f2bf(acc[m][n][3]);
          *(ushort4*)&dst[((size_t)(b*H_ + h)*DK_ + d)*S_ + s0] = o;
        }
    } else {
#pragma unroll
      for (int m = 0; m < 4; ++m)
#pragma unroll
        for (int n = 0; n < 4; ++n) {
          const int row0 = m0 + wr*64 + m*16 + (lane >> 4)*4;
          const int col  = n0 + wc*64 + n*16 + (lane & 15);
          const int h = col >> 6, d = col & 63;
          const float sgn = (d & 1) ? 1.0f : -1.0f;
#pragma unroll
          for (int r = 0; r < 4; ++r) {
            const int row = row0 + r;
            const int b = row >> 11, s = row & (S_ - 1);
            float v  = acc[m][n][r];
            float pv = __shfl_xor(v, 1);          // pair partner: col^1 == lane^1
            float2 cs = tab[s*32 + (d >> 1)];
            float ov = v * cs.x + sgn * pv * cs.y;
            dst[((size_t)(b*H_ + h)*S_ + s)*DK_ + d] = f2bf(ov);
          }
        }
    }
  }
}

// ---------------- causal flash attention, barrier-free ----------------
// 512 blocks (XCD-swizzled), 4 waves; each wave owns 32 q-rows independently.
// K loaded direct global->frag ([bh][s][dk]); V direct from V^T ([bh][dk][s]).
// Only LDS: wave-private P repack buffer (no __syncthreads anywhere).
__global__ __launch_bounds__(256) void k_attn(
    const unsigned short* __restrict__ Qg,   // [B*H][S][DK]
    const unsigned short* __restrict__ Kg,   // [B*H][S][DK]
    const unsigned short* __restrict__ Vtg,  // [B*H][DK][S]
    unsigned short* __restrict__ Og)         // [B][S][D]
{
  __shared__ unsigned short Ps[4][16*72];    // per-wave P tile, stride 72

  const int tid = threadIdx.x, lane = tid & 63, w = tid >> 6;
  // XCD swizzle: 64 consecutive work-items per XCD -> 4 heads' KV resident in one L2
  const int nb = (blockIdx.x & 7) * 64 + (blockIdx.x >> 3);
  const int head = nb >> 4;                  // 0..31 (= b*16+h)
  const int qb = nb & 15;
  const int q0w = qb * 128 + w * 32;         // this wave's first q row
  const int c = lane & 15, hg = lane >> 4;

  const unsigned short* Qp = Qg + ((size_t)head * S_ + q0w) * DK_;
  const unsigned short* Kp = Kg + (size_t)head * S_ * DK_;
  const unsigned short* Vp = Vtg + (size_t)head * DK_ * S_;

  bf16x8 aq[2][2];
#pragma unroll
  for (int m = 0; m < 2; ++m)
#pragma unroll
    for (int kk = 0; kk < 2; ++kk)
      aq[m][kk] = *(const bf16x8*)(Qp + (size_t)(m*16 + c)*DK_ + kk*32 + hg*8);

  f32x4 oacc[2][4];
  float mrow[2][4], lrow[2][4];
#pragma unroll
  for (int m = 0; m < 2; ++m) {
#pragma unroll
    for (int n = 0; n < 4; ++n) oacc[m][n] = (f32x4){0.f, 0.f, 0.f, 0.f};
#pragma unroll
    for (int r = 0; r < 4; ++r) { mrow[m][r] = -INFINITY; lrow[m][r] = 0.f; }
  }

  const float SC = 0.125f * 1.44269504088896f;   // 1/sqrt(dk) * log2(e)
  const int nkv = (q0w >> 6) + 1;

  for (int t = 0; t < nkv; ++t) {
    const int kv0 = t * 64;

    // fragment loads, direct from global (L1/L2-served; no LDS, no barriers)
    bf16x8 bk[4][2], bv[4][2];
#pragma unroll
    for (int n = 0; n < 4; ++n)
#pragma unroll
      for (int kk = 0; kk < 2; ++kk) {
        bk[n][kk] = *(const bf16x8*)(Kp + (size_t)(kv0 + n*16 + c)*DK_ + kk*32 + hg*8);
        bv[n][kk] = *(const bf16x8*)(Vp + (size_t)(n*16 + c)*S_ + kv0 + kk*32 + hg*8);
      }

    // ---- QK^T
    f32x4 sc4[2][4];
#pragma unroll
    for (int m = 0; m < 2; ++m)
#pragma unroll
      for (int n = 0; n < 4; ++n) {
        sc4[m][n] = (f32x4){0.f, 0.f, 0.f, 0.f};
#pragma unroll
        for (int kk = 0; kk < 2; ++kk)
          sc4[m][n] = __builtin_amdgcn_mfma_f32_16x16x32_bf16(aq[m][kk], bk[n][kk], sc4[m][n], 0, 0, 0);
      }

    const bool domask = (t == nkv - 1);

#pragma unroll
    for (int m = 0; m < 2; ++m) {
      // scale to exp2 domain (+ causal mask on last step only)
#pragma unroll
      for (int n = 0; n < 4; ++n)
#pragma unroll
        for (int r = 0; r < 4; ++r)
          sc4[m][n][r] *= SC;
      if (domask) {
        const int qr = q0w + m*16 + hg*4;
#pragma unroll
        for (int n = 0; n < 4; ++n)
#pragma unroll
          for (int r = 0; r < 4; ++r)
            if (kv0 + n*16 + c > qr + r) sc4[m][n][r] = -INFINITY;
      }

      // online softmax: row max (16-lane reduce), rescale, exp2, row sum
      float pm[4];
#pragma unroll
      for (int r = 0; r < 4; ++r)
        pm[r] = fmaxf(fmaxf(sc4[m][0][r], sc4[m][1][r]), fmaxf(sc4[m][2][r], sc4[m][3][r]));
#pragma unroll
      for (int off = 1; off < 16; off <<= 1)
#pragma unroll
        for (int r = 0; r < 4; ++r)
          pm[r] = fmaxf(pm[r], __shfl_xor(pm[r], off));

      float alpha[4];
#pragma unroll
      for (int r = 0; r < 4; ++r) {
        float mn = fmaxf(mrow[m][r], pm[r]);
        alpha[r] = exp2f(mrow[m][r] - mn);
        mrow[m][r] = mn;
      }

      float psum[4] = {0.f, 0.f, 0.f, 0.f};
#pragma unroll
      for (int n = 0; n < 4; ++n)
#pragma unroll
        for (int r = 0; r < 4; ++r) {
          float p = exp2f(sc4[m][n][r] - mrow[m][r]);
          sc4[m][n][r] = p;
          psum[r] += p;
        }
#pragma unroll
      for (int off = 1; off < 16; off <<= 1)
#pragma unroll
        for (int r = 0; r < 4; ++r)
          psum[r] += __shfl_xor(psum[r], off);

#pragma unroll
      for (int r = 0; r < 4; ++r) lrow[m][r] = lrow[m][r]*alpha[r] + psum[r];

      // P -> LDS (wave-private; compiler orders write->read via lgkmcnt)
#pragma unroll
      for (int n = 0; n < 4; ++n)
#pragma unroll
        for (int r = 0; r < 4; ++r)
          Ps[w][(hg*4 + r)*72 + n*16 + c] = f2bf(sc4[m][n][r]);

#pragma unroll
      for (int n = 0; n < 4; ++n)
#pragma unroll
        for (int r = 0; r < 4; ++r)
          oacc[m][n][r] *= alpha[r];

      // ---- PV: oacc[q][d] += P[q][kv] * V^T[d][kv]
      bf16x8 ap[2];
#pragma unroll
      for (int kk = 0; kk < 2; ++kk)
        ap[kk] = *(const bf16x8*)&Ps[w][c*72 + kk*32 + hg*8];
#pragma unroll
      for (int n = 0; n < 4; ++n)
#pragma unroll
        for (int kk = 0; kk < 2; ++kk)
          oacc[m][n] = __builtin_amdgcn_mfma_f32_16x16x32_bf16(ap[kk], bv[n][kk], oacc[m][n], 0, 0, 0);
    }
  }

  const int b = head >> 4, h = head & 15;
#pragma unroll
  for (int m = 0; m < 2; ++m) {
    float rl[4];
#pragma unroll
    for (int r = 0; r < 4; ++r) rl[r] = 1.0f / lrow[m][r];
#pragma unroll
    for (int n = 0; n < 4; ++n)
#pragma unroll
      for (int r = 0; r < 4; ++r) {
        const int s = q0w + m*16 + hg*4 + r;
        const int d = n*16 + c;
        Og[((size_t)b*S_ + s)*D_ + h*DK_ + d] = f2bf(oacc[m][n][r] * rl[r]);
      }
  }
}

// ---------------- launcher ----------------
extern "C" void kernel_launch(void* const* d_in, const int* in_sizes, int n_in,
                              void* d_out, int out_size, void* d_ws, size_t ws_size,
                              hipStream_t stream) {
  const float* x = (const float*)d_in[0];
  const float* Wm[4] = {(const float*)d_in[1], (const float*)d_in[2],
                        (const float*)d_in[3], (const float*)d_in[4]};
  const int* tp = (const int*)d_in[5];
  float* out = (float*)d_out;

  unsigned short* ws = (unsigned short*)d_ws;
  const size_t MD = (size_t)M_ * D_;                 // 4M elements
  unsigned short* xb  = ws;                          // x bf16; reused as attn buffer
  unsigned short* wb  = ws + MD;                     // 4 weight mats bf16
  unsigned short* qws = ws + MD + 4*(size_t)D_*K_;   // Q,K (row-major), V^T
  float2* tab = (float2*)(ws + MD + 4*(size_t)D_*K_ + 3*MD);  // [S][32]

  k_f2b<<<dim3((int)(MD/4/256)), 256, 0, stream>>>(x, xb, (int)MD);
  for (int i = 0; i < 4; ++i)
    k_f2b<<<dim3((int)((size_t)D_*K_/4/256)), 256, 0, stream>>>(Wm[i], wb + (size_t)i*D_*K_, D_*K_);
  k_rope_tab<<<dim3(S_*32/256), 256, 0, stream>>>(tp, tab);

  k_gemm<0><<<dim3(M_/128, D_/128, 3), 256, 0, stream>>>(xb, wb, qws, nullptr, tab);

  unsigned short* attn = xb;   // x no longer needed
  k_attn<<<dim3(512), 256, 0, stream>>>(qws, qws + MD, qws + 2*MD, attn);

  k_gemm<1><<<dim3(M_/128, D_/128, 1), 256, 0, stream>>>(attn, wb, nullptr, out, tab);
}